// Round 15
// baseline (177.836 us; speedup 1.0000x reference)
//
#include <hip/hip_runtime.h>

#define BB 64
#define PP 100
#define NN 1000
#define DDIM 128
#define HH 8
#define NSPL 8

typedef __attribute__((ext_vector_type(8))) short bf16x8;   // 8 bf16 = 4 VGPRs
typedef __attribute__((ext_vector_type(16))) float f32x16;  // MFMA 32x32 acc
typedef __attribute__((ext_vector_type(4))) unsigned u32x4;
typedef __attribute__((ext_vector_type(2))) unsigned u32x2;

__device__ __forceinline__ unsigned bf16rne(float x) {
  unsigned u = __float_as_uint(x);
  return (u + 0x7FFFu + ((u >> 16) & 1u)) >> 16;
}
__device__ __forceinline__ unsigned pk_bf16(float a, float b) {
  return bf16rne(a) | (bf16rne(b) << 16);
}

// split 8 contiguous floats into hi/lo bf16x8 fragments
__device__ __forceinline__ void split8(const float* __restrict__ p,
                                       bf16x8& hi8, bf16x8& lo8) {
  const float4 a = *(const float4*)p;
  const float4 c = *(const float4*)(p + 4);
  float v[8] = {a.x, a.y, a.z, a.w, c.x, c.y, c.z, c.w};
  unsigned hw[4], lw[4];
#pragma unroll
  for (int j = 0; j < 4; ++j) {
    const unsigned h0 = bf16rne(v[2*j]), h1 = bf16rne(v[2*j+1]);
    hw[j] = h0 | (h1 << 16);
    lw[j] = bf16rne(v[2*j]   - __uint_as_float(h0 << 16)) |
            (bf16rne(v[2*j+1] - __uint_as_float(h1 << 16)) << 16);
  }
  hi8 = __builtin_bit_cast(bf16x8, u32x4{hw[0], hw[1], hw[2], hw[3]});
  lo8 = __builtin_bit_cast(bf16x8, u32x4{lw[0], lw[1], lw[2], lw[3]});
}

// ---------------------------------------------------------------------------
// pack 5 weight matrices (fp32 128x128) -> MFMA B-fragment layout, split
// hi/lo bf16. mat: 0=Wk 1=Wv 2=Wq_first 3=Wq_last 4=W_comb. (unchanged)
// ---------------------------------------------------------------------------
__global__ __launch_bounds__(256) void pack_w_kernel(
    const float* __restrict__ W0, const float* __restrict__ W1,
    const float* __restrict__ W2, const float* __restrict__ W3,
    const float* __restrict__ W4, u32x4* __restrict__ wfrag)
{
  const int gid = blockIdx.x * 256 + threadIdx.x;  // [0, 10240)
  const int mat = gid >> 11;
  const int ct = (gid >> 9) & 3;
  const int ks = (gid >> 6) & 7;
  const int lane = gid & 63;
  const float* __restrict__ W =
      (mat == 0) ? W0 : (mat == 1) ? W1 : (mat == 2) ? W2 : (mat == 3) ? W3 : W4;
  const int col = ct * 32 + (lane & 31);
  const int k0 = ks * 16 + (lane >> 5) * 8;
  unsigned hi[4], lo[4];
#pragma unroll
  for (int j = 0; j < 4; ++j) {
    const float x0 = W[(k0 + 2 * j) * DDIM + col];
    const float x1 = W[(k0 + 2 * j + 1) * DDIM + col];
    const unsigned h0 = bf16rne(x0), h1 = bf16rne(x1);
    hi[j] = h0 | (h1 << 16);
    lo[j] = bf16rne(x0 - __uint_as_float(h0 << 16)) |
            (bf16rne(x1 - __uint_as_float(h1 << 16)) << 16);
  }
  const int base = (((mat * 4 + ct) * 8 + ks) * 2) * 64 + lane;
  wfrag[base]      = u32x4{hi[0], hi[1], hi[2], hi[3]};
  wfrag[base + 64] = u32x4{lo[0], lo[1], lo[2], lo[3]};
}

// ---------------------------------------------------------------------------
// pack enc_nodes -> fragment layout, split hi/lo bf16. (unchanged, r14)
// ---------------------------------------------------------------------------
__global__ __launch_bounds__(512) void pack_enc_kernel(
    const float* __restrict__ enc, u32x4* __restrict__ encp)
{
  const int b = blockIdx.x >> 5;
  const int t = blockIdx.x & 31;
  const int ks = threadIdx.x >> 6;
  const int lane = threadIdx.x & 63;
  const int n = min(32 * t + (lane & 31), NN - 1);
  const int k0 = ks * 16 + (lane >> 5) * 8;
  bf16x8 hi8, lo8;
  split8(enc + ((size_t)b * NN + n) * DDIM + k0, hi8, lo8);
  const size_t base = ((size_t)(b * 32 + t) * 8 + ks) * 128 + lane;
  encp[base]      = __builtin_bit_cast(u32x4, hi8);
  encp[base + 64] = __builtin_bit_cast(u32x4, lo8);
}

// ---------------------------------------------------------------------------
// pack mh -> A-fragment layout for score2. (unchanged, r14)
// ---------------------------------------------------------------------------
__global__ __launch_bounds__(512) void pack_mh_kernel(
    const float* __restrict__ mh, u32x4* __restrict__ mhp)
{
  const int b = blockIdx.x >> 2;
  const int mt = blockIdx.x & 3;
  const int ks = threadIdx.x >> 6;
  const int lane = threadIdx.x & 63;
  const int p = min(32 * mt + (lane & 31), PP - 1);
  const int k0 = ks * 16 + (lane >> 5) * 8;
  bf16x8 hi8, lo8;
  split8(mh + ((size_t)b * PP + p) * DDIM + k0, hi8, lo8);
  const size_t base = ((size_t)(b * 4 + mt) * 8 + ks) * 128 + lane;
  mhp[base]      = __builtin_bit_cast(u32x4, hi8);
  mhp[base + 64] = __builtin_bit_cast(u32x4, lo8);
}

// ---------------------------------------------------------------------------
// K+V projection via MFMA, round-15: per-b grid (b = blk>>3, 128 local rows;
// rows >=NN clamped on read, skipped on K write). K written row-major fp32
// as before. V emitted DIRECTLY in attn's B-fragment layout (Vp, split
// hi/lo) from the C-layout accumulators via the permlane32_swap routing
// verified in r13 -- kills attn's 64-scattered-dword V gather + ~560 VALU
// pack instr per thread. Vp slot: [(((b*32+t)*2+g)*8+h)*2+half]*32
// + (lane>>5)*16 + (l31&15).
// grid = BB*8.
// ---------------------------------------------------------------------------
__global__ __launch_bounds__(256) void proj_kv_mfma_kernel(
    const float* __restrict__ x, const u32x4* __restrict__ wfrag,
    float* __restrict__ outk, u32x4* __restrict__ vp)
{
  const int tid = threadIdx.x;
  const int lane = tid & 63;
  const int wid = tid >> 6;
  const int rtp = wid >> 1;
  const int ctp = wid & 1;
  const int b = blockIdx.x >> 3;
  const int blk8 = blockIdx.x & 7;
  const int rloc0 = blk8 * 128 + rtp * 64 + (lane & 31);  // + rt*32
  const int kgrp = (lane >> 5) * 8;
  const int l31 = lane & 31;
  const float* xb = x + (size_t)b * NN * DDIM;

#pragma unroll 1
  for (int mat = 0; mat < 2; ++mat) {
    f32x16 acc[2][2];
#pragma unroll
    for (int a = 0; a < 2; ++a)
#pragma unroll
      for (int c = 0; c < 2; ++c)
#pragma unroll
        for (int i = 0; i < 16; ++i) acc[a][c][i] = 0.f;

#pragma unroll 1
    for (int ks = 0; ks < 8; ++ks) {
      bf16x8 ahi[2], alo[2];
#pragma unroll
      for (int rt = 0; rt < 2; ++rt) {
        const int arow = min(rloc0 + rt * 32, NN - 1);
        split8(xb + (size_t)arow * DDIM + ks * 16 + kgrp, ahi[rt], alo[rt]);
      }
#pragma unroll
      for (int ct = 0; ct < 2; ++ct) {
        const int c = ctp * 2 + ct;
        const int fo = (((mat * 4 + c) * 8 + ks) * 2) * 64 + lane;
        const bf16x8 bhi = __builtin_bit_cast(bf16x8, wfrag[fo]);
        const bf16x8 blo = __builtin_bit_cast(bf16x8, wfrag[fo + 64]);
#pragma unroll
        for (int rt = 0; rt < 2; ++rt) {
          acc[rt][ct] = __builtin_amdgcn_mfma_f32_32x32x16_bf16(
              ahi[rt], bhi, acc[rt][ct], 0, 0, 0);
          acc[rt][ct] = __builtin_amdgcn_mfma_f32_32x32x16_bf16(
              ahi[rt], blo, acc[rt][ct], 0, 0, 0);
          acc[rt][ct] = __builtin_amdgcn_mfma_f32_32x32x16_bf16(
              alo[rt], bhi, acc[rt][ct], 0, 0, 0);
        }
      }
    }

    if (mat == 0) {
      // K: row-major fp32 write (rows >= NN skipped)
#pragma unroll
      for (int rt = 0; rt < 2; ++rt)
#pragma unroll
        for (int ct = 0; ct < 2; ++ct) {
          const int colg = ctp * 64 + ct * 32 + l31;
          const int rowl0 = blk8 * 128 + rtp * 64 + rt * 32 + 4 * (lane >> 5);
#pragma unroll
          for (int r = 0; r < 16; ++r) {
            const int rowl = rowl0 + (r & 3) + 8 * (r >> 2);
            if (rowl < NN)
              outk[((size_t)b * NN + rowl) * DDIM + colg] = acc[rt][ct][r];
          }
        }
    } else {
      // V: emit B-fragments via permlane routing (clamp rows are junk,
      // multiplied by P=0 in attn)
#pragma unroll
      for (int rt = 0; rt < 2; ++rt) {
        const int t = blk8 * 4 + rtp * 2 + rt;
#pragma unroll
        for (int ct = 0; ct < 2; ++ct) {
          const int h = ctp * 4 + ct * 2 + (l31 >> 4);
          const int dcol = l31 & 15;
#pragma unroll
          for (int g = 0; g < 2; ++g) {
            unsigned hw[4], lw[4];
#pragma unroll
            for (int j = 0; j < 4; ++j) {
              const float a0 = acc[rt][ct][8 * g + 2 * j];
              const float a1 = acc[rt][ct][8 * g + 2 * j + 1];
              const unsigned h0 = bf16rne(a0), h1 = bf16rne(a1);
              hw[j] = h0 | (h1 << 16);
              lw[j] = bf16rne(a0 - __uint_as_float(h0 << 16)) |
                      (bf16rne(a1 - __uint_as_float(h1 << 16)) << 16);
            }
            const u32x2 rh0 = __builtin_amdgcn_permlane32_swap(hw[0], hw[2], false, false);
            const u32x2 rh1 = __builtin_amdgcn_permlane32_swap(hw[1], hw[3], false, false);
            const u32x2 rl0 = __builtin_amdgcn_permlane32_swap(lw[0], lw[2], false, false);
            const u32x2 rl1 = __builtin_amdgcn_permlane32_swap(lw[1], lw[3], false, false);
            const size_t sb = ((((size_t)(b * 32 + t) * 2 + g) * 8 + h) * 2) * 32
                              + (lane >> 5) * 16 + dcol;
            vp[sb]      = u32x4{rh0[0], rh1[0], rh0[1], rh1[1]};
            vp[sb + 32] = u32x4{rl0[0], rl1[0], rl0[1], rl1[1]};
          }
        }
      }
    }
  }
}

// ---------------------------------------------------------------------------
// Q projection via MFMA: out = (x1@Wq_first + x2@Wq_last) * scale. (r9)
// ---------------------------------------------------------------------------
__global__ __launch_bounds__(256) void proj_q2_mfma_kernel(
    const float* __restrict__ x1, const float* __restrict__ x2,
    const u32x4* __restrict__ wfrag, float* __restrict__ out, float scale)
{
  const int tid = threadIdx.x;
  const int lane = tid & 63;
  const int w = tid >> 6;
  const int hi = lane >> 5;
  const int l31 = lane & 31;
  const int row0 = blockIdx.x * 128 + w * 32;
  const float* xr1 = x1 + (size_t)(row0 + l31) * DDIM + hi * 8;
  const float* xr2 = x2 + (size_t)(row0 + l31) * DDIM + hi * 8;

  f32x16 acc[4];
#pragma unroll
  for (int ct = 0; ct < 4; ++ct)
#pragma unroll
    for (int i = 0; i < 16; ++i) acc[ct][i] = 0.f;

#pragma unroll 1
  for (int ks = 0; ks < 8; ++ks) {
    bf16x8 a1h, a1l, a2h, a2l;
    split8(xr1 + ks * 16, a1h, a1l);
    split8(xr2 + ks * 16, a2h, a2l);
#pragma unroll
    for (int ct = 0; ct < 4; ++ct) {
      const int fo1 = (((2 * 4 + ct) * 8 + ks) * 2) * 64 + lane;  // Wq_first
      const bf16x8 b1h = __builtin_bit_cast(bf16x8, wfrag[fo1]);
      const bf16x8 b1l = __builtin_bit_cast(bf16x8, wfrag[fo1 + 64]);
      acc[ct] = __builtin_amdgcn_mfma_f32_32x32x16_bf16(a1h, b1h, acc[ct], 0, 0, 0);
      acc[ct] = __builtin_amdgcn_mfma_f32_32x32x16_bf16(a1h, b1l, acc[ct], 0, 0, 0);
      acc[ct] = __builtin_amdgcn_mfma_f32_32x32x16_bf16(a1l, b1h, acc[ct], 0, 0, 0);
      const int fo2 = (((3 * 4 + ct) * 8 + ks) * 2) * 64 + lane;  // Wq_last
      const bf16x8 b2h = __builtin_bit_cast(bf16x8, wfrag[fo2]);
      const bf16x8 b2l = __builtin_bit_cast(bf16x8, wfrag[fo2 + 64]);
      acc[ct] = __builtin_amdgcn_mfma_f32_32x32x16_bf16(a2h, b2h, acc[ct], 0, 0, 0);
      acc[ct] = __builtin_amdgcn_mfma_f32_32x32x16_bf16(a2h, b2l, acc[ct], 0, 0, 0);
      acc[ct] = __builtin_amdgcn_mfma_f32_32x32x16_bf16(a2l, b2h, acc[ct], 0, 0, 0);
    }
  }
#pragma unroll
  for (int ct = 0; ct < 4; ++ct) {
    const int colg = ct * 32 + l31;
    const int rowg0 = row0 + 4 * hi;
#pragma unroll
    for (int r = 0; r < 16; ++r) {
      const int rowg = rowg0 + (r & 3) + 8 * (r >> 2);
      out[(size_t)rowg * DDIM + colg] = acc[ct][r] * scale;
    }
  }
}

// ---------------------------------------------------------------------------
// Combine projection via MFMA: out = x@W_comb + bias. (r9)
// ---------------------------------------------------------------------------
__global__ __launch_bounds__(256) void proj_comb_mfma_kernel(
    const float* __restrict__ x, const u32x4* __restrict__ wfrag,
    const float* __restrict__ bias, float* __restrict__ out)
{
  const int tid = threadIdx.x;
  const int lane = tid & 63;
  const int w = tid >> 6;
  const int hi = lane >> 5;
  const int l31 = lane & 31;
  const int row0 = blockIdx.x * 128 + w * 32;
  const float* xr = x + (size_t)(row0 + l31) * DDIM + hi * 8;

  f32x16 acc[4];
#pragma unroll
  for (int ct = 0; ct < 4; ++ct)
#pragma unroll
    for (int i = 0; i < 16; ++i) acc[ct][i] = 0.f;

#pragma unroll 1
  for (int ks = 0; ks < 8; ++ks) {
    bf16x8 ah, al;
    split8(xr + ks * 16, ah, al);
#pragma unroll
    for (int ct = 0; ct < 4; ++ct) {
      const int fo = (((4 * 4 + ct) * 8 + ks) * 2) * 64 + lane;  // W_comb
      const bf16x8 bh = __builtin_bit_cast(bf16x8, wfrag[fo]);
      const bf16x8 bl = __builtin_bit_cast(bf16x8, wfrag[fo + 64]);
      acc[ct] = __builtin_amdgcn_mfma_f32_32x32x16_bf16(ah, bh, acc[ct], 0, 0, 0);
      acc[ct] = __builtin_amdgcn_mfma_f32_32x32x16_bf16(ah, bl, acc[ct], 0, 0, 0);
      acc[ct] = __builtin_amdgcn_mfma_f32_32x32x16_bf16(al, bh, acc[ct], 0, 0, 0);
    }
  }
#pragma unroll
  for (int ct = 0; ct < 4; ++ct) {
    const int colg = ct * 32 + l31;
    const float bj = bias[colg];
    const int rowg0 = row0 + 4 * hi;
#pragma unroll
    for (int r = 0; r < 16; ++r) {
      const int rowg = rowg0 + (r & 3) + 8 * (r >> 2);
      out[(size_t)rowg * DDIM + colg] = acc[ct][r] + bj;
    }
  }
}

// ---------------------------------------------------------------------------
// MFMA attention, round-15: V from prepacked Vp (coalesced dwordx4) --
// round-14 version gathered 64 scattered dwords + ~560 pack instr/thread.
// K split8, mask-as-C-in, -inf pad, permlane P-routing unchanged (r13).
// ---------------------------------------------------------------------------
__global__ __launch_bounds__(512) void attn_mfma_kernel(
    const float* __restrict__ Q, const float* __restrict__ K,
    const u32x4* __restrict__ vp, const float* __restrict__ mask,
    float* __restrict__ po, float* __restrict__ lsum)
{
  __shared__ float mask_lds[PP * 132];   // [p][n-chunk], pad 132 for banks

  const int b = blockIdx.x >> 3;
  const int chunk = blockIdx.x & 7;
  const int n0 = chunk * 128;
  const int tid = threadIdx.x;
  const int h = tid >> 6;          // wave = head
  const int l = tid & 63;
  const int hi = l >> 5;
  const int l31 = l & 31;

  const float NINF = -__builtin_huge_valf();
  for (int idx = tid; idx < PP * 32; idx += 512) {
    const int p = idx >> 5;
    const int c = idx & 31;
    const int nb4 = n0 + 4 * c;
    const int nsrc = min(nb4, NN - 4);
    float4 f = *(const float4*)(mask + ((size_t)(b * PP + p)) * NN + nsrc);
    f.x = (nb4 + 0 < NN) ? f.x : NINF;   // pad columns n>=NN kill via exp(-inf)
    f.y = (nb4 + 1 < NN) ? f.y : NINF;
    f.z = (nb4 + 2 < NN) ? f.z : NINF;
    f.w = (nb4 + 3 < NN) ? f.w : NINF;
    *(float4*)&mask_lds[p * 132 + 4 * c] = f;
  }
  __syncthreads();

  bf16x8 qhi[4], qlo[4];
#pragma unroll
  for (int pt = 0; pt < 4; ++pt) {
    const int qrow = min(b * PP + pt * 32 + l31, BB * PP - 1);
    split8(Q + (size_t)qrow * DDIM + h * 16 + hi * 8, qhi[pt], qlo[pt]);
  }

  f32x16 oacc[4];
#pragma unroll
  for (int pt = 0; pt < 4; ++pt)
#pragma unroll
    for (int i = 0; i < 16; ++i) oacc[pt][i] = 0.f;
  float lacc[4] = {0.f, 0.f, 0.f, 0.f};

  const float* Kb = K + (size_t)b * NN * DDIM + h * 16;

#pragma unroll 1
  for (int nt = 0; nt < 4; ++nt) {
    const int nb = n0 + nt * 32;
    const int t = chunk * 4 + nt;

    bf16x8 khi, klo;
    {
      const int krow = min(nb + l31, NN - 1);
      split8(Kb + (size_t)krow * DDIM + hi * 8, khi, klo);
    }
    bf16x8 vhi[2], vlo[2];
#pragma unroll
    for (int ks = 0; ks < 2; ++ks) {
      const size_t sb = ((((size_t)(b * 32 + t) * 2 + ks) * 8 + h) * 2) * 32
                        + (size_t)hi * 16 + (l31 & 15);
      vhi[ks] = __builtin_bit_cast(bf16x8, vp[sb]);
      vlo[ks] = __builtin_bit_cast(bf16x8, vp[sb + 32]);
    }

#pragma unroll
    for (int pt = 0; pt < 4; ++pt) {
      // S^T = K.Q^T with mask as C-in (layout of mq matches C exactly)
      const int prow = min(pt * 32 + l31, PP - 1);
      f32x16 s;
#pragma unroll
      for (int q = 0; q < 4; ++q) {
        const float4 f =
            *(const float4*)&mask_lds[prow * 132 + nt * 32 + q * 8 + hi * 4];
        s[4*q+0] = f.x; s[4*q+1] = f.y; s[4*q+2] = f.z; s[4*q+3] = f.w;
      }
      s = __builtin_amdgcn_mfma_f32_32x32x16_bf16(khi, qhi[pt], s, 0, 0, 0);
      s = __builtin_amdgcn_mfma_f32_32x32x16_bf16(khi, qlo[pt], s, 0, 0, 0);
      s = __builtin_amdgcn_mfma_f32_32x32x16_bf16(klo, qhi[pt], s, 0, 0, 0);

      float ev[16];
#pragma unroll
      for (int r = 0; r < 16; ++r) {
        const float e = __expf(s[r]);   // pad/masked cols: exp(-inf)=0
        ev[r] = e;
        lacc[pt] += e;
      }
      unsigned u[8];
#pragma unroll
      for (int j = 0; j < 8; ++j) u[j] = pk_bf16(ev[2*j], ev[2*j+1]);
      // route C-layout P -> A-frag via permlane32_swap (VALU half-exchange)
#pragma unroll
      for (int ks = 0; ks < 2; ++ks) {
        const unsigned t01 = u[ks*4+0], t23 = u[ks*4+1];
        const unsigned t45 = u[ks*4+2], t67 = u[ks*4+3];
        const u32x2 r0 = __builtin_amdgcn_permlane32_swap(t01, t45, false, false);
        const u32x2 r1 = __builtin_amdgcn_permlane32_swap(t23, t67, false, false);
        const bf16x8 pah = __builtin_bit_cast(bf16x8,
            u32x4{r0[0], r1[0], r0[1], r1[1]});
        oacc[pt] = __builtin_amdgcn_mfma_f32_32x32x16_bf16(pah, vhi[ks], oacc[pt], 0, 0, 0);
        oacc[pt] = __builtin_amdgcn_mfma_f32_32x32x16_bf16(pah, vlo[ks], oacc[pt], 0, 0, 0);
      }
    }
  }

  const int base = (b * NSPL + chunk) * PP;
#pragma unroll
  for (int pt = 0; pt < 4; ++pt) {
    const float ltot = lacc[pt] + __shfl_xor(lacc[pt], 32, 64);
    const int pl = pt * 32 + l31;
    if (l < 32 && pl < PP)
      lsum[(size_t)(base + pl) * HH + h] = ltot;
#pragma unroll
    for (int r = 0; r < 16; ++r) {
      const int p = pt * 32 + (r & 3) + 8 * (r >> 2) + 4 * hi;
      if (l31 < 16 && p < PP)
        po[(size_t)(base + p) * DDIM + h * 16 + l31] = oacc[pt][r];
    }
  }
}

// ---------------------------------------------------------------------------
// merge: mh_in[b][p][d] = (sum_s po) / (sum_s lsum[h(d)])  (unchanged)
// ---------------------------------------------------------------------------
__global__ __launch_bounds__(256) void merge_kernel(
    const float* __restrict__ po, const float* __restrict__ lsum,
    float* __restrict__ mh_in)
{
  const int idx = blockIdx.x * 256 + threadIdx.x;   // over BB*PP*DDIM
  const int d = idx & 127;
  const int row = idx >> 7;        // b*PP + p
  const int b = row / PP;
  const int p = row - b * PP;
  const int h = d >> 4;
  float s = 0.f, lt = 0.f;
#pragma unroll
  for (int sp = 0; sp < NSPL; ++sp) {
    const int base = (b * NSPL + sp) * PP + p;
    s  += po[base * DDIM + d];
    lt += lsum[base * HH + h];
  }
  mh_in[idx] = s / lt;
}

// ---------------------------------------------------------------------------
// score2 via MFMA with prepacked operands + fused epilogue. (unchanged, r14)
// ---------------------------------------------------------------------------
__global__ __launch_bounds__(256) void score2_mfma_kernel(
    const u32x4* __restrict__ encp, const u32x4* __restrict__ mhp,
    const float* __restrict__ mask, const float* __restrict__ bias_table,
    const int* __restrict__ group_ids, const int* __restrict__ cur_min,
    float* __restrict__ out, float* __restrict__ ssum)
{
  const int b   = blockIdx.x >> 4;
  const int nc  = blockIdx.x & 15;
  const int n0  = nc * 64;
  const int tid = threadIdx.x;
  const int lane = tid & 63;
  const int mt   = tid >> 6;
  const int half = lane >> 5;
  const int l31  = lane & 31;

  f32x16 acc[2];
#pragma unroll
  for (int c = 0; c < 2; ++c)
#pragma unroll
    for (int i = 0; i < 16; ++i) acc[c][i] = 0.f;

  const u32x4* ma  = mhp  + ((size_t)(b * 4 + mt) * 8) * 128 + lane;
  const u32x4* eb0 = encp + ((size_t)(b * 32 + nc * 2) * 8) * 128 + lane;
  const u32x4* eb1 = encp + ((size_t)(b * 32 + nc * 2 + 1) * 8) * 128 + lane;

#pragma unroll 2
  for (int ks = 0; ks < 8; ++ks) {
    const bf16x8 ahi  = __builtin_bit_cast(bf16x8, ma[ks * 128]);
    const bf16x8 alo  = __builtin_bit_cast(bf16x8, ma[ks * 128 + 64]);
    const bf16x8 bhi0 = __builtin_bit_cast(bf16x8, eb0[ks * 128]);
    const bf16x8 blo0 = __builtin_bit_cast(bf16x8, eb0[ks * 128 + 64]);
    const bf16x8 bhi1 = __builtin_bit_cast(bf16x8, eb1[ks * 128]);
    const bf16x8 blo1 = __builtin_bit_cast(bf16x8, eb1[ks * 128 + 64]);
    acc[0] = __builtin_amdgcn_mfma_f32_32x32x16_bf16(ahi, bhi0, acc[0], 0, 0, 0);
    acc[0] = __builtin_amdgcn_mfma_f32_32x32x16_bf16(ahi, blo0, acc[0], 0, 0, 0);
    acc[0] = __builtin_amdgcn_mfma_f32_32x32x16_bf16(alo, bhi0, acc[0], 0, 0, 0);
    acc[1] = __builtin_amdgcn_mfma_f32_32x32x16_bf16(ahi, bhi1, acc[1], 0, 0, 0);
    acc[1] = __builtin_amdgcn_mfma_f32_32x32x16_bf16(ahi, blo1, acc[1], 0, 0, 0);
    acc[1] = __builtin_amdgcn_mfma_f32_32x32x16_bf16(alo, bhi1, acc[1], 0, 0, 0);
  }

  const float t0 = bias_table[0], t1 = bias_table[1], t2 = bias_table[2],
              t3 = bias_table[3], t4 = bias_table[4];
  const float two_inv_sqrt_emb = 0.1767766952966369f;  // 2/sqrt(128)

  // hoist per-row cur_min (independent of ct)
  int cmpv[16];
#pragma unroll
  for (int r = 0; r < 16; ++r) {
    const int p = 32 * mt + (r & 3) + 8 * (r >> 2) + 4 * half;
    cmpv[r] = cur_min[b * PP + min(p, PP - 1)];
  }

  float rsum[16];
#pragma unroll
  for (int r = 0; r < 16; ++r) rsum[r] = 0.f;

#pragma unroll
  for (int ct = 0; ct < 2; ++ct) {
    const int n = n0 + ct * 32 + l31;
    const bool nvalid = n < NN;
    const int nr = nvalid ? n : NN - 1;
    const int gid = group_ids[b * NN + nr];
#pragma unroll
    for (int r = 0; r < 16; ++r) {
      const int p = 32 * mt + (r & 3) + 8 * (r >> 2) + 4 * half;
      const bool pvalid = p < PP;
      const int pr = pvalid ? p : PP - 1;
      const float m = mask[((size_t)(b * PP + pr)) * NN + nr];
      const float ex = __expf(acc[ct][r] * two_inv_sqrt_emb);
      const float sc = 10.0f - 20.0f / (ex + 1.0f);
      int delta = gid - cmpv[r];
      delta = delta < 0 ? 0 : (delta > 4 ? 4 : delta);
      const float pb = (delta == 0) ? t0 : (delta == 1) ? t1 : (delta == 2) ? t2
                     : (delta == 3) ? t3 : t4;
      float e = (nvalid && pvalid) ? __expf(sc + pb + m) : 0.0f;
      if (nvalid && pvalid) out[((size_t)(b * PP + p)) * NN + n] = e;
      rsum[r] += e;
    }
  }
  // one reduce tree per row (hoisted out of ct loop)
#pragma unroll
  for (int r = 0; r < 16; ++r) {
    float ws = rsum[r];
#pragma unroll
    for (int off = 1; off < 32; off <<= 1) ws += __shfl_xor(ws, off, 64);
    rsum[r] = ws;
  }
  if (l31 == 0) {
#pragma unroll
    for (int r = 0; r < 16; ++r) {
      const int p = 32 * mt + (r & 3) + 8 * (r >> 2) + 4 * half;
      if (p < PP) ssum[(size_t)(b * PP + p) * 16 + nc] = rsum[r];
    }
  }
}

// ---------------------------------------------------------------------------
// normalize: out[row][n] /= sum of 16 chunk partials  (unchanged)
// ---------------------------------------------------------------------------
__global__ __launch_bounds__(256) void norm_kernel(
    const float* __restrict__ ssum, float* __restrict__ out)
{
  const int row = blockIdx.x;   // b*PP + p
  float s = 0.f;
#pragma unroll
  for (int i = 0; i < 16; ++i) s += ssum[(size_t)row * 16 + i];
  const float inv = 1.0f / s;
#pragma unroll
  for (int i = 0; i < 4; ++i) {
    const int c = i * 256 + (int)threadIdx.x;
    if (c < NN) out[(size_t)row * NN + c] *= inv;
  }
}

// ---------------------------------------------------------------------------
extern "C" void kernel_launch(void* const* d_in, const int* in_sizes, int n_in,
                              void* d_out, int out_size, void* d_ws, size_t ws_size,
                              hipStream_t stream)
{
  (void)in_sizes; (void)n_in; (void)out_size; (void)ws_size;
  const float* enc_nodes  = (const float*)d_in[0];
  const float* enc_q1     = (const float*)d_in[1];
  const float* enc_last   = (const float*)d_in[2];
  const float* ninf       = (const float*)d_in[3];
  const float* Wq_first   = (const float*)d_in[4];
  const float* Wq_last    = (const float*)d_in[5];
  const float* Wk         = (const float*)d_in[6];
  const float* Wv         = (const float*)d_in[7];
  const float* W_comb     = (const float*)d_in[8];
  const float* b_comb     = (const float*)d_in[9];
  const float* bias_table = (const float*)d_in[10];
  const int*   group_ids  = (const int*)d_in[11];
  const int*   cur_min    = (const int*)d_in[12];
  float* out = (float*)d_out;
  float* ws  = (float*)d_ws;

  float* Qw = ws;                    //   819200 floats (reused as mh_in after attn)
  float* Kw = Qw + 819200;           //  8192000 floats
  u32x4* Vp = (u32x4*)(Kw + 8192000);//  2097152 u32x4 (33.55MB, packed V frags)
  float* po = Kw + 8192000 + 8388608;//  6553600  (BB*NSPL*PP*DDIM)
  float* ls = po + 6553600;          //   409600  (BB*NSPL*PP*HH)
  float* mh = ls + 409600;           //   819200
  float* sm = mh + 819200;           //   102400  (BB*PP*16)

  // wfrag (320 KB, 5 matrices) aliases sm: consumed by proj kernels
  // (steps 2,3,6); sm first written by score2 (step 7) -- stream-safe.
  u32x4* wfrag = (u32x4*)sm;
  // encp (33.5 MB) + mhp (4 MB) alias Kw+Vp: both dead after attn (step 4);
  // packed after merge, consumed by score2. Fits in 66.3 MB region.
  u32x4* encp = (u32x4*)Kw;                 // 2,097,152 u32x4
  u32x4* mhp  = ((u32x4*)Kw) + 2097152;     //   262,144 u32x4

  // pack all 5 weight matrices into split-bf16 MFMA fragments
  pack_w_kernel<<<40, 256, 0, stream>>>(Wk, Wv, Wq_first, Wq_last, W_comb, wfrag);
  // Q = (q1@Wq_first + last@Wq_last) * 0.25 via MFMA (fold 1/sqrt(QD))
  proj_q2_mfma_kernel<<<BB*PP/128, 256, 0, stream>>>(enc_q1, enc_last, wfrag,
                                                     Qw, 0.25f);
  // K (row-major) + V (packed B-frags) via split-bf16 MFMA, per-b grid
  proj_kv_mfma_kernel<<<BB*8, 256, 0, stream>>>(enc_nodes, wfrag, Kw, Vp);
  // attention partials via MFMA (V from packed frags)
  attn_mfma_kernel<<<BB*NSPL, 512, 0, stream>>>(Qw, Kw, Vp, ninf, po, ls);
  // merge partials -> mh_in (reuses Qw)
  merge_kernel<<<3200, 256, 0, stream>>>(po, ls, Qw);
  // pack enc into fragment layout (K/V buffers now dead)
  pack_enc_kernel<<<BB*32, 512, 0, stream>>>(enc_nodes, encp);
  // combine: mh = mh_in @ W_comb + b_comb via MFMA
  proj_comb_mfma_kernel<<<BB*PP/128, 256, 0, stream>>>(Qw, wfrag, b_comb, mh);
  // pack mh into A-fragment layout
  pack_mh_kernel<<<BB*4, 512, 0, stream>>>(mh, mhp);
  // final scores via MFMA (prepacked operands) + fused epilogue
  score2_mfma_kernel<<<BB*16, 256, 0, stream>>>(encp, mhp, ninf, bias_table,
                                                group_ids, cur_min, out, sm);
  // normalize
  norm_kernel<<<BB*PP, 256, 0, stream>>>(sm, out);
}